// Round 6
// baseline (424.155 us; speedup 1.0000x reference)
//
#include <hip/hip_runtime.h>
#include <stdint.h>

typedef unsigned short u16;
typedef __attribute__((ext_vector_type(8))) short short8;
typedef __attribute__((ext_vector_type(4))) float f32x4;

#define KGU  5120
#define HCOL 27648
#define NPD  2560
#define KD   27648
#define SPLITD 12
#define KCHD 2304            // 27648/12
#define PEL (256*2560)

__device__ __forceinline__ void gl_lds16(const void* gp, void* lp) {
  __builtin_amdgcn_global_load_lds((const __attribute__((address_space(1))) uint32_t*)gp,
                                   (__attribute__((address_space(3))) uint32_t*)lp, 16, 0, 0);
}
__device__ __forceinline__ uint32_t f2bf(float x) {
  uint32_t b = __float_as_uint(x);
  return (b + 0x7fffu + ((b >> 16) & 1u)) >> 16;
}
__device__ __forceinline__ uint32_t pk2(float lo, float hi) { return f2bf(lo) | (f2bf(hi) << 16); }
__device__ __forceinline__ uint32_t cvtpk(float lo, float hi) {
  uint32_t r;
  asm("v_cvt_pk_bf16_f32 %0, %1, %2" : "=v"(r) : "v"(lo), "v"(hi));
  return r;
}
__device__ __forceinline__ float silu(float x) {
  return x * __builtin_amdgcn_rcpf(1.f + __expf(-x));
}

// ---------------- kernel 0: x fp32 -> bf16 ----------------
__global__ __launch_bounds__(256) void k_cvt(const float* __restrict__ X, u16* __restrict__ Xb) {
  int i = (blockIdx.x * 256 + threadIdx.x) * 8;
  float4 a = *(const float4*)(X + i);
  float4 b = *(const float4*)(X + i + 4);
  uint4 v;
  v.x = pk2(a.x, a.y); v.y = pk2(a.z, a.w); v.z = pk2(b.x, b.y); v.w = pk2(b.z, b.w);
  *(uint4*)(Xb + i) = v;
}

// ---------------- kernel 1: gate+up GEMM (BM=128 x 128 interleaved cols, BK=32) ----------------
// 256 thr / 4 waves (2M x 2N), wave 64x64. Deep pipeline: B-regs dist-4, A gl_lds dist-3,
// vmcnt(12) steady (never waits same-iter loads). Granule-swizzled LDS (conflict-free b128).
__global__ __launch_bounds__(256, 2)
void k_gu(const u16* __restrict__ X,
          const float* __restrict__ Wg, const float* __restrict__ bg,
          const float* __restrict__ W1g, const float* __restrict__ b1g,
          const float* __restrict__ W2g, const float* __restrict__ b2g,
          const float* __restrict__ Wu, const float* __restrict__ bu,
          const float* __restrict__ W1u, const float* __restrict__ b1u,
          const float* __restrict__ W2u, const float* __restrict__ b2u,
          u16* __restrict__ H) {
  __shared__ __align__(16) char smem[50688];   // A 4x8KB | B 2x8KB | consts 1.5KB
  const int tid = threadIdx.x, lane = tid & 63, wid = tid >> 6;
  const int wm = wid >> 1, wn = wid & 1;
  const int s_ = lane & 15, quad = lane >> 4;
  // XCD-chunked swizzle: 432 = 8 x 54; m-twins (2j,2j+1) land on same XCD, 8 dispatches apart
  const int h = blockIdx.x;
  const int w = (h & 7) * 54 + (h >> 3);
  const int m0 = (w & 1) * 128;
  const int j0 = (w >> 1) * 64;                // 64 j-pairs = 128 interleaved cols

  float4* mc4 = (float4*)(smem + 49152);
  float*  mc1 = (float*)(smem + 49152 + 1024);
  if (tid < 64) {
    int sel = tid >> 5, m = tid & 31;
    const float* w1 = (sel ? W1u : W1g) + m * 6;
    const float* b1 = sel ? b1u : b1g;
    const float* w2 = sel ? W2u : W2g;
    mc4[sel * 32 + m] = make_float4(w1[0] + w1[2] + w1[4], w1[1] + w1[3] + w1[5], b1[m], w2[m]);
    mc1[sel * 32 + m] = w2[32 + m];
  }

  // LDS granule swizzle: stored granule = logical ^ ((row>>1)&3); reads use quad^((s_>>1)&3)
  const int sw = quad ^ ((s_ >> 1) & 3);
  // A: wave owns rows [32wid,32wid+32); gl_lds dest linear, source pre-swizzled
  const u16* srcA0 = X + (size_t)(m0 + 32 * wid + (lane >> 2)) * KGU
                       + (((lane & 3) ^ ((lane >> 3) & 3)) << 3);
  const u16* srcA1 = srcA0 + (size_t)16 * KGU;
  const int dA0 = wid * 2048, dA1 = dA0 + 1024;
  // B: 2 thr/row; row r even->Wg[j0+r/2], odd->Wu[j0+r/2]
  const int br = tid >> 1, bh = tid & 1;
  const float* srcB = ((br & 1) ? Wu : Wg) + (size_t)(j0 + (br >> 1)) * KGU + bh * 16;
  const int bpair = (bh ^ ((br >> 2) & 1)) << 5;    // swizzled 32B pair slot
  const int bo_sw = ((br >> 1) & 1) << 4;           // intra-pair swap
  const int aoffc = (wm * 64 + s_) * 64 + sw * 16;  // + mi*1024
  const int boffc = (wn * 64 + s_) * 64 + sw * 16;  // + ni*1024

  f32x4 acc[4][4];
#pragma unroll
  for (int i = 0; i < 4; ++i)
#pragma unroll
    for (int j = 0; j < 4; ++j) acc[i][j] = (f32x4)0.f;

  float4 Bq[4][4];
  auto loadB = [&](float4* q, int tk) {
    const float* p = srcB + tk * 32;
#pragma unroll
    for (int i = 0; i < 4; ++i) q[i] = *(const float4*)(p + i * 4);
  };
  auto stageA = [&](int ab, int tk) {
    gl_lds16(srcA0 + tk * 32, smem + ab + dA0);
    gl_lds16(srcA1 + tk * 32, smem + ab + dA1);
  };
  auto writeB = [&](int bb, const float4* q) {
    uint4 v0, v1;
    v0.x = cvtpk(q[0].x, q[0].y); v0.y = cvtpk(q[0].z, q[0].w);
    v0.z = cvtpk(q[1].x, q[1].y); v0.w = cvtpk(q[1].z, q[1].w);
    v1.x = cvtpk(q[2].x, q[2].y); v1.y = cvtpk(q[2].z, q[2].w);
    v1.z = cvtpk(q[3].x, q[3].y); v1.w = cvtpk(q[3].z, q[3].w);
    char* p = smem + bb + br * 64 + bpair;
    *(uint4*)(p + bo_sw) = v0;
    *(uint4*)(p + (bo_sw ^ 16)) = v1;
  };
  auto compute = [&](int ab, int bb) {
    const char* base = smem;
    short8 af[4], bf[4];
#pragma unroll
    for (int mi = 0; mi < 4; ++mi) af[mi] = *(const short8*)(base + ab + aoffc + mi * 1024);
#pragma unroll
    for (int ni = 0; ni < 4; ++ni) bf[ni] = *(const short8*)(base + bb + boffc + ni * 1024);
    __builtin_amdgcn_s_setprio(1);
#pragma unroll
    for (int mi = 0; mi < 4; ++mi)
#pragma unroll
      for (int ni = 0; ni < 4; ++ni)
        acc[mi][ni] = __builtin_amdgcn_mfma_f32_16x16x32_bf16(af[mi], bf[ni], acc[mi][ni], 0, 0, 0);
    __builtin_amdgcn_s_setprio(0);
  };

  // prologue: A tiles 0..2 staged, B tiles 0..3 in regs, B0 -> LDS
  stageA(0, 0); stageA(8192, 1); stageA(16384, 2);
  loadB(Bq[0], 0); loadB(Bq[1], 1); loadB(Bq[2], 2); loadB(Bq[3], 3);
  asm volatile("s_waitcnt vmcnt(12)" ::: "memory");
  writeB(32768, Bq[0]);
  asm volatile("s_waitcnt lgkmcnt(0)" ::: "memory");
  __builtin_amdgcn_s_barrier();

#pragma unroll 1
  for (int tb = 0; tb < 40; ++tb) {
    const int t0 = tb * 4;
#pragma unroll
    for (int j = 0; j < 4; ++j) {
      const int t = t0 + j;
      loadB(Bq[j], (t + 4 < 160) ? t + 4 : 159);          // B(t+4)
      stageA(((j + 3) & 3) * 8192, (t + 3 < 160) ? t + 3 : 159);  // A(t+3)
      compute(j * 8192, 32768 + (j & 1) * 8192);          // tile t
      asm volatile("s_waitcnt vmcnt(12)" ::: "memory");   // A(t+1),B(t+1) ready
      writeB(32768 + ((j + 1) & 1) * 8192, Bq[(j + 1) & 3]);
      asm volatile("s_waitcnt lgkmcnt(0)" ::: "memory");
      __builtin_amdgcn_s_barrier();
    }
  }

  // ---- fused epilogue: qrun per lane (gate even / up odd), shfl pair, silu*up ----
  const int sel = lane & 1;
  const float b2v0 = sel ? b2u[0] : b2g[0];
  const float b2v1 = sel ? b2u[1] : b2g[1];
  const float4* mcs = mc4 + sel * 32;
  const float*  mcw = mc1 + sel * 32;
#pragma unroll
  for (int ni = 0; ni < 4; ++ni) {
    const int c = wn * 64 + ni * 16 + s_;
    const int j = j0 + (c >> 1);
    const float bp = sel ? bu[j] : bg[j];
#pragma unroll
    for (int mi = 0; mi < 4; ++mi) {
      float sv[4], cv[4], o0[4], o1[4];
#pragma unroll
      for (int e = 0; e < 4; ++e) {
        float p = acc[mi][ni][e] + bp;
        sv[e] = __sinf(p); cv[e] = __cosf(p);
        o0[e] = b2v0; o1[e] = b2v1;
      }
#pragma unroll 4
      for (int m = 0; m < 32; ++m) {
        float4 k4 = mcs[m]; float w2b = mcw[m];
#pragma unroll
        for (int e = 0; e < 4; ++e) {
          float hh = fmaxf(fmaf(sv[e], k4.x, fmaf(cv[e], k4.y, k4.z)), 0.f);
          o0[e] = fmaf(hh, k4.w, o0[e]);
          o1[e] = fmaf(hh, w2b, o1[e]);
        }
      }
#pragma unroll
      for (int e = 0; e < 4; ++e) {
        float t0 = __shfl_xor(o0[e], 1);
        float t1 = __shfl_xor(o1[e], 1);
        float g0 = sel ? t0 : o0[e];
        float u0 = sel ? o0[e] : t0;
        float g1 = sel ? t1 : o1[e];
        float u1 = sel ? o1[e] : t1;
        float h0 = silu(g0) * u0, h1 = silu(g1) * u1;
        if (!sel) {
          const int row = m0 + wm * 64 + mi * 16 + quad * 4 + e;
          *(uint32_t*)&H[(size_t)row * HCOL + 2 * j] = pk2(h0, h1);
        }
      }
    }
  }
}

// ---------------- kernel 2: down GEMM (BM=128 x BN=128, BK=32, splitK=12) ----------------
__global__ __launch_bounds__(256, 2)
void k_down(const u16* __restrict__ Hb, const float* __restrict__ Wd, float* __restrict__ P2) {
  __shared__ __align__(16) char smem[49152];
  const int tid = threadIdx.x, lane = tid & 63, wid = tid >> 6;
  const int wm = wid >> 1, wn = wid & 1;
  const int s_ = lane & 15, quad = lane >> 4;
  const int hx = blockIdx.x;                    // 40 = 8 x 5
  const int w = (hx & 7) * 5 + (hx >> 3);
  const int m0 = (w & 1) * 128;
  const int n0 = (w >> 1) * 128;
  const int kc = blockIdx.y * KCHD;

  const int sw = quad ^ ((s_ >> 1) & 3);
  const u16* srcA0 = Hb + (size_t)(m0 + 32 * wid + (lane >> 2)) * KD + kc
                        + (((lane & 3) ^ ((lane >> 3) & 3)) << 3);
  const u16* srcA1 = srcA0 + (size_t)16 * KD;
  const int dA0 = wid * 2048, dA1 = dA0 + 1024;
  const int br = tid >> 1, bh = tid & 1;
  const float* srcB = Wd + (size_t)(n0 + br) * KD + kc + bh * 16;
  const int bpair = (bh ^ ((br >> 2) & 1)) << 5;
  const int bo_sw = ((br >> 1) & 1) << 4;
  const int aoffc = (wm * 64 + s_) * 64 + sw * 16;
  const int boffc = (wn * 64 + s_) * 64 + sw * 16;

  f32x4 acc[4][4];
#pragma unroll
  for (int i = 0; i < 4; ++i)
#pragma unroll
    for (int j = 0; j < 4; ++j) acc[i][j] = (f32x4)0.f;

  float4 Bq[4][4];
  auto loadB = [&](float4* q, int tk) {
    const float* p = srcB + tk * 32;
#pragma unroll
    for (int i = 0; i < 4; ++i) q[i] = *(const float4*)(p + i * 4);
  };
  auto stageA = [&](int ab, int tk) {
    gl_lds16(srcA0 + tk * 32, smem + ab + dA0);
    gl_lds16(srcA1 + tk * 32, smem + ab + dA1);
  };
  auto writeB = [&](int bb, const float4* q) {
    uint4 v0, v1;
    v0.x = cvtpk(q[0].x, q[0].y); v0.y = cvtpk(q[0].z, q[0].w);
    v0.z = cvtpk(q[1].x, q[1].y); v0.w = cvtpk(q[1].z, q[1].w);
    v1.x = cvtpk(q[2].x, q[2].y); v1.y = cvtpk(q[2].z, q[2].w);
    v1.z = cvtpk(q[3].x, q[3].y); v1.w = cvtpk(q[3].z, q[3].w);
    char* p = smem + bb + br * 64 + bpair;
    *(uint4*)(p + bo_sw) = v0;
    *(uint4*)(p + (bo_sw ^ 16)) = v1;
  };
  auto compute = [&](int ab, int bb) {
    short8 af[4], bf[4];
#pragma unroll
    for (int mi = 0; mi < 4; ++mi) af[mi] = *(const short8*)(smem + ab + aoffc + mi * 1024);
#pragma unroll
    for (int ni = 0; ni < 4; ++ni) bf[ni] = *(const short8*)(smem + bb + boffc + ni * 1024);
    __builtin_amdgcn_s_setprio(1);
#pragma unroll
    for (int mi = 0; mi < 4; ++mi)
#pragma unroll
      for (int ni = 0; ni < 4; ++ni)
        acc[mi][ni] = __builtin_amdgcn_mfma_f32_16x16x32_bf16(af[mi], bf[ni], acc[mi][ni], 0, 0, 0);
    __builtin_amdgcn_s_setprio(0);
  };

  stageA(0, 0); stageA(8192, 1); stageA(16384, 2);
  loadB(Bq[0], 0); loadB(Bq[1], 1); loadB(Bq[2], 2); loadB(Bq[3], 3);
  asm volatile("s_waitcnt vmcnt(12)" ::: "memory");
  writeB(32768, Bq[0]);
  asm volatile("s_waitcnt lgkmcnt(0)" ::: "memory");
  __builtin_amdgcn_s_barrier();

#pragma unroll 1
  for (int tb = 0; tb < 18; ++tb) {             // 72 K-tiles
    const int t0 = tb * 4;
#pragma unroll
    for (int j = 0; j < 4; ++j) {
      const int t = t0 + j;
      loadB(Bq[j], (t + 4 < 72) ? t + 4 : 71);
      stageA(((j + 3) & 3) * 8192, (t + 3 < 72) ? t + 3 : 71);
      compute(j * 8192, 32768 + (j & 1) * 8192);
      asm volatile("s_waitcnt vmcnt(12)" ::: "memory");
      writeB(32768 + ((j + 1) & 1) * 8192, Bq[(j + 1) & 3]);
      asm volatile("s_waitcnt lgkmcnt(0)" ::: "memory");
      __builtin_amdgcn_s_barrier();
    }
  }

  const size_t pb = (size_t)blockIdx.y * PEL;
#pragma unroll
  for (int mi = 0; mi < 4; ++mi) {
    int mrow = m0 + wm * 64 + mi * 16 + (quad << 2);
#pragma unroll
    for (int ni = 0; ni < 4; ++ni) {
      int n = n0 + wn * 64 + ni * 16 + s_;
#pragma unroll
      for (int e = 0; e < 4; ++e)
        P2[pb + (size_t)(mrow + e) * NPD + n] = acc[mi][ni][e];
    }
  }
}

// ---------------- kernel 3: reduce partials + QRUN-d epilogue -> out fp32 ----------------
__global__ __launch_bounds__(256) void k_fin(const float* __restrict__ P2, const float* __restrict__ bd,
    const float* __restrict__ W1d, const float* __restrict__ b1d, const float* __restrict__ W2d,
    const float* __restrict__ b2d, float* __restrict__ out) {
  __shared__ float4 mc0[32];
  __shared__ float mc1[32];
  const int tid = threadIdx.x;
  if (tid < 32) {
    const float* w = W1d + tid * 6;
    mc0[tid] = make_float4(w[0] + w[2] + w[4], w[1] + w[3] + w[5], b1d[tid], W2d[tid]);
    mc1[tid] = W2d[32 + tid];
  }
  __syncthreads();
  const int idx = blockIdx.x * 256 + tid;
  const int m = idx / NPD, j = idx - m * NPD;
  float p = bd[j];
#pragma unroll
  for (int sk = 0; sk < SPLITD; ++sk) p += P2[(size_t)sk * PEL + idx];
  float s = __sinf(p), c = __cosf(p);
  float o0 = b2d[0], o1 = b2d[1];
#pragma unroll 4
  for (int mm = 0; mm < 32; ++mm) {
    float4 k = mc0[mm];
    float hh = fmaxf(fmaf(s, k.x, fmaf(c, k.y, k.z)), 0.f);
    o0 = fmaf(hh, k.w, o0);
    o1 = fmaf(hh, mc1[mm], o1);
  }
  *(float2*)&out[(size_t)m * 5120 + 2 * j] = make_float2(o0, o1);
}

extern "C" void kernel_launch(void* const* d_in, const int* in_sizes, int n_in,
                              void* d_out, int out_size, void* d_ws, size_t ws_size,
                              hipStream_t stream) {
  const float* x   = (const float*)d_in[0];
  const float* Wg  = (const float*)d_in[1];
  const float* bg  = (const float*)d_in[2];
  const float* W1g = (const float*)d_in[3];
  const float* b1g = (const float*)d_in[4];
  const float* W2g = (const float*)d_in[5];
  const float* b2g = (const float*)d_in[6];
  const float* Wu  = (const float*)d_in[7];
  const float* bu  = (const float*)d_in[8];
  const float* W1u = (const float*)d_in[9];
  const float* b1u = (const float*)d_in[10];
  const float* W2u = (const float*)d_in[11];
  const float* b2u = (const float*)d_in[12];
  const float* Wd  = (const float*)d_in[13];
  const float* bd  = (const float*)d_in[14];
  const float* W1d = (const float*)d_in[15];
  const float* b1d = (const float*)d_in[16];
  const float* W2d = (const float*)d_in[17];
  const float* b2d = (const float*)d_in[18];
  char* ws = (char*)d_ws;
  u16*  xb = (u16*)ws;                    // 2,621,440 B
  u16*  hb = (u16*)(ws + 2621440);        // 14,155,776 B (ends 16,777,216)
  float* P2 = (float*)(ws + 16777216);    // 12 x 655360 x 4 = 31,457,280 B
  if (ws_size < 48234496u) return;

  k_cvt<<<dim3(640), dim3(256), 0, stream>>>(x, xb);
  k_gu<<<dim3(432), dim3(256), 0, stream>>>(xb, Wg, bg, W1g, b1g, W2g, b2g,
                                            Wu, bu, W1u, b1u, W2u, b2u, hb);
  k_down<<<dim3(40, SPLITD), dim3(256), 0, stream>>>(hb, Wd, P2);
  k_fin<<<dim3(2560), dim3(256), 0, stream>>>(P2, bd, W1d, b1d, W2d, b2d, (float*)d_out);
}

// Round 7
// 299.632 us; speedup vs baseline: 1.4156x; 1.4156x over previous
//
#include <hip/hip_runtime.h>
#include <stdint.h>

typedef unsigned short u16;
typedef __attribute__((ext_vector_type(8))) short short8;
typedef __attribute__((ext_vector_type(4))) float f32x4;

#define KGU  5120
#define NPD  2560
#define KD   27648
#define SPLITD 12
#define KCHD 2304            // 27648/12
#define PEL (256*2560)

__device__ __forceinline__ uint32_t f2bf(float x) {
  uint32_t b = __float_as_uint(x);
  return (b + 0x7fffu + ((b >> 16) & 1u)) >> 16;
}
__device__ __forceinline__ uint32_t pk2(float lo, float hi) { return f2bf(lo) | (f2bf(hi) << 16); }
__device__ __forceinline__ uint32_t cvtpk(float lo, float hi) {
  uint32_t r;
  asm("v_cvt_pk_bf16_f32 %0, %1, %2" : "=v"(r) : "v"(lo), "v"(hi));
  return r;
}
__device__ __forceinline__ float silu(float x) {
  return x * __builtin_amdgcn_rcpf(1.f + __expf(-x));
}
#define MFMA16(a,b,c) __builtin_amdgcn_mfma_f32_16x16x32_bf16(a, b, c, 0, 0, 0)

// ---------------- kernel 0: x fp32 -> XF bf16, MFMA-fragment order ----------------
// XF[kt 0..159][mt 0..15][lane 0..63][8 bf16]; frag lane l: x[mt*16+(l&15)][kt*32+(l>>4)*8+e]
__global__ __launch_bounds__(256) void k_cvt(const float* __restrict__ X, u16* __restrict__ XF) {
  const int kt = blockIdx.x;
  const int lane = threadIdx.x & 63, wv = threadIdx.x >> 6;
#pragma unroll
  for (int ii = 0; ii < 4; ++ii) {
    const int mt = wv * 4 + ii;
    const float* src = X + (size_t)(mt * 16 + (lane & 15)) * KGU + kt * 32 + (lane >> 4) * 8;
    float4 f0 = *(const float4*)src;
    float4 f1 = *(const float4*)(src + 4);
    uint4 v;
    v.x = cvtpk(f0.x, f0.y); v.y = cvtpk(f0.z, f0.w);
    v.z = cvtpk(f1.x, f1.y); v.w = cvtpk(f1.z, f1.w);
    *(uint4*)(XF + ((size_t)(kt * 16 + mt) * 64 + lane) * 8) = v;
  }
}

// ---------------- kernel 1: gate+up GEMM, BM=256 x 64 interleaved cols, supertile SK=256 ----
// 512 thr / 8 waves (4M x 2N), wave 64x32. Grid 432 (j-tiles), XCD-chunked.
// B: per supertile each wave loads 8 weight rows as 1KB-contiguous instrs -> cvt -> swizzled LDS.
// A: direct global->VGPR fragment loads from XF (1KB-contiguous, L2-resident). 1 barrier/supertile.
__global__ __launch_bounds__(512, 4)
void k_gu(const u16* __restrict__ XF,
          const float* __restrict__ Wg, const float* __restrict__ bg,
          const float* __restrict__ W1g, const float* __restrict__ b1g,
          const float* __restrict__ W2g, const float* __restrict__ b2g,
          const float* __restrict__ Wu, const float* __restrict__ bu,
          const float* __restrict__ W1u, const float* __restrict__ b1u,
          const float* __restrict__ W2u, const float* __restrict__ b2u,
          u16* __restrict__ HF) {
  __shared__ __align__(16) char smem[66560];     // 2 x 32KB B-tiles + 1.5KB consts
  const int tid = threadIdx.x, lane = tid & 63, wid = tid >> 6;
  const int wm = wid >> 1, wn = wid & 1;
  const int s_ = lane & 15, quad = lane >> 4;
  const int bx = blockIdx.x;
  const int w = (bx & 7) * 54 + (bx >> 3);       // XCD-chunked
  const int j0p = w * 32;                        // 32 channel-pairs per tile

  float4* mc4 = (float4*)(smem + 65536);
  float*  mc1 = (float*)(smem + 65536 + 1024);
  if (tid < 64) {
    int sel = tid >> 5, m = tid & 31;
    const float* w1 = (sel ? W1u : W1g) + m * 6;
    const float* b1 = sel ? b1u : b1g;
    const float* w2 = sel ? W2u : W2g;
    mc4[sel * 32 + m] = make_float4(w1[0] + w1[2] + w1[4], w1[1] + w1[3] + w1[5], b1[m], w2[m]);
    mc1[sel * 32 + m] = w2[32 + m];
  }

  // staging: wave stages tile-rows r = 8*wid + i (i=0..7); row r <-> output col c=r:
  //   channel j = j0p + 4*wid + (i>>1), matrix = (i&1) ? Wu : Wg. 1KB contiguous per row-instr.
  const int kkl = lane >> 3;                     // k-block of this lane's 16B
  const int s0 = 8 * (wid & 1);
  const int wbase = kkl * 4096 + (wid >> 1) * 1024 + ((lane >> 1) & 3) * 256 + (lane & 1) * 8;
  const float* srcG = Wg + (size_t)(j0p + 4 * wid) * KGU + 4 * lane;
  const float* srcU = Wu + (size_t)(j0p + 4 * wid) * KGU + 4 * lane;

  const int rbase = quad * 256 + (s_ << 4);
  const short8* XFp = (const short8*)XF;

  f32x4 acc[4][2];
#pragma unroll
  for (int i = 0; i < 4; ++i) { acc[i][0] = (f32x4)0.f; acc[i][1] = (f32x4)0.f; }

  float4 sr[8];
#pragma unroll
  for (int i = 0; i < 8; ++i) {
    const float* p = ((i & 1) ? srcU : srcG) + (size_t)(i >> 1) * KGU;
    sr[i] = *(const float4*)p;
  }

#pragma unroll 1
  for (int st = 0; st < 20; ++st) {
    char* buf = smem + (st & 1) * 32768;
    // convert staged regs -> swizzled bf16 LDS tile [kk 0..7][cf 0..3][64][16B]
#pragma unroll
    for (int i = 0; i < 8; ++i) {
      uint2 v; v.x = cvtpk(sr[i].x, sr[i].y); v.y = cvtpk(sr[i].z, sr[i].w);
      *(uint2*)(buf + wbase + (((s0 + i) ^ kkl) << 4)) = v;
    }
    __builtin_amdgcn_sched_barrier(0);
    if (st < 19) {                               // issue next supertile's loads NOW
      const int kf = (st + 1) * 256;
#pragma unroll
      for (int i = 0; i < 8; ++i) {
        const float* p = ((i & 1) ? srcU : srcG) + (size_t)(i >> 1) * KGU + kf;
        sr[i] = *(const float4*)p;
      }
    }
    __builtin_amdgcn_sched_barrier(0);
    asm volatile("s_waitcnt lgkmcnt(0)" ::: "memory");
    __builtin_amdgcn_s_barrier();
    __builtin_amdgcn_sched_barrier(0);
    // 8 K-steps of pure compute (A direct from XF, B from LDS)
    const short8* pa = XFp + ((size_t)(st * 8) * 16 + wm * 4) * 64 + lane;
    const char* bb = buf + (wn * 2) * 1024;
#pragma unroll
    for (int kk = 0; kk < 8; ++kk) {
      short8 a0 = pa[(kk * 16 + 0) * 64];
      short8 a1 = pa[(kk * 16 + 1) * 64];
      short8 a2 = pa[(kk * 16 + 2) * 64];
      short8 a3 = pa[(kk * 16 + 3) * 64];
      const int ro = kk * 4096 + (rbase ^ (kk << 4));
      short8 b0 = *(const short8*)(bb + ro);
      short8 b1 = *(const short8*)(bb + ro + 1024);
      __builtin_amdgcn_s_setprio(1);
      acc[0][0] = MFMA16(a0, b0, acc[0][0]); acc[0][1] = MFMA16(a0, b1, acc[0][1]);
      acc[1][0] = MFMA16(a1, b0, acc[1][0]); acc[1][1] = MFMA16(a1, b1, acc[1][1]);
      acc[2][0] = MFMA16(a2, b0, acc[2][0]); acc[2][1] = MFMA16(a2, b1, acc[2][1]);
      acc[3][0] = MFMA16(a3, b0, acc[3][0]); acc[3][1] = MFMA16(a3, b1, acc[3][1]);
      __builtin_amdgcn_s_setprio(0);
    }
    // no trailing barrier needed: double-buffer + leading barrier make WAR safe
  }

  // ---- fused epilogue: qrun per lane (gate even / up odd), shfl pair, silu*up -> HF frags ----
  const int sel = lane & 1;
  const float b2v0 = sel ? b2u[0] : b2g[0];
  const float b2v1 = sel ? b2u[1] : b2g[1];
  const float4* mcs = mc4 + sel * 32;
  const float*  mcw = mc1 + sel * 32;
  char* HFb = (char*)HF;
#pragma unroll
  for (int ni = 0; ni < 2; ++ni) {
    const int c = wn * 32 + ni * 16 + s_;
    const int j = j0p + (c >> 1);
    const float bp = sel ? bu[j] : bg[j];
#pragma unroll
    for (int mi = 0; mi < 4; ++mi) {
      float sv[4], cv[4], o0[4], o1[4];
#pragma unroll
      for (int e = 0; e < 4; ++e) {
        float p = acc[mi][ni][e] + bp;
        sv[e] = __sinf(p); cv[e] = __cosf(p);
        o0[e] = b2v0; o1[e] = b2v1;
      }
#pragma unroll 4
      for (int m = 0; m < 32; ++m) {
        float4 k4 = mcs[m]; float w2b = mcw[m];
#pragma unroll
        for (int e = 0; e < 4; ++e) {
          float hh = fmaxf(fmaf(sv[e], k4.x, fmaf(cv[e], k4.y, k4.z)), 0.f);
          o0[e] = fmaf(hh, k4.w, o0[e]);
          o1[e] = fmaf(hh, w2b, o1[e]);
        }
      }
#pragma unroll
      for (int e = 0; e < 4; ++e) {
        float t0 = __shfl_xor(o0[e], 1);
        float t1 = __shfl_xor(o1[e], 1);
        float g0 = sel ? t0 : o0[e];
        float u0 = sel ? o0[e] : t0;
        float g1 = sel ? t1 : o1[e];
        float u1 = sel ? o1[e] : t1;
        float h0 = silu(g0) * u0, h1 = silu(g1) * u1;
        if (!sel) {
          // write h[row][2j],[2j+1] into HF fragment layout for k_down's A
          const int row = wm * 64 + mi * 16 + quad * 4 + e;
          const int kt2 = j >> 4, mt2 = wm * 4 + mi;
          const int lf2 = (row & 15) + 16 * ((j >> 2) & 3);
          *(uint32_t*)(HFb + (size_t)(kt2 * 16 + mt2) * 1024 + lf2 * 16 + (j & 3) * 4)
              = pk2(h0, h1);
        }
      }
    }
  }
}

// ---------------- kernel 2: down GEMM, BM=256 x BN=128, supertile SK=128, splitK=12 ----------
// 512 thr / 8 waves (4M x 2N), wave 64x64. Grid 240. A-frags direct from HF (L3-resident).
__global__ __launch_bounds__(512, 2)
void k_down(const u16* __restrict__ HF, const float* __restrict__ Wd, float* __restrict__ P2) {
  __shared__ __align__(16) char smem[65536];     // 2 x 32KB
  const int tid = threadIdx.x, lane = tid & 63, wid = tid >> 6;
  const int wm = wid >> 1, wn = wid & 1;
  const int s_ = lane & 15, quad = lane >> 4;
  const int bx = blockIdx.x;                     // 240 = 8 x 30
  const int w = (bx & 7) * 30 + (bx >> 3);
  const int sk = w / 20, nt = w % 20;            // same-sk blocks cluster per XCD (HF L2 reuse)
  const int n0 = nt * 128;
  const int kc = sk * KCHD;

  // staging: wave stages rows r = 16*wid + 2i + (lane>>5); 512B contiguous per half-instr
  const int b5 = lane >> 5;
  const float* srcD = Wd + (size_t)(n0 + 16 * wid + b5) * KD + kc + 4 * (lane & 31);
  const int kkd = (lane & 31) >> 3;              // 0..3
  const int wbase = kkd * 8192 + wid * 1024 + ((lane & 7) >> 1) * 256 + (lane & 1) * 8;
  const int rbase = quad * 256 + (s_ << 4);
  const short8* HFp = (const short8*)HF;
  const int kc32 = sk * 72;

  f32x4 acc[4][4];
#pragma unroll
  for (int i = 0; i < 4; ++i)
#pragma unroll
    for (int j = 0; j < 4; ++j) acc[i][j] = (f32x4)0.f;

  float4 sr[8];
#pragma unroll
  for (int i = 0; i < 8; ++i) sr[i] = *(const float4*)(srcD + (size_t)(2 * i) * KD);

#pragma unroll 1
  for (int st = 0; st < 18; ++st) {
    char* buf = smem + (st & 1) * 32768;
#pragma unroll
    for (int i = 0; i < 8; ++i) {
      uint2 v; v.x = cvtpk(sr[i].x, sr[i].y); v.y = cvtpk(sr[i].z, sr[i].w);
      *(uint2*)(buf + wbase + (((2 * i + b5) ^ kkd) << 4)) = v;
    }
    __builtin_amdgcn_sched_barrier(0);
    if (st < 17) {
      const int kf = (st + 1) * 128;
#pragma unroll
      for (int i = 0; i < 8; ++i)
        sr[i] = *(const float4*)(srcD + (size_t)(2 * i) * KD + kf);
    }
    __builtin_amdgcn_sched_barrier(0);
    asm volatile("s_waitcnt lgkmcnt(0)" ::: "memory");
    __builtin_amdgcn_s_barrier();
    __builtin_amdgcn_sched_barrier(0);
    const short8* pa = HFp + ((size_t)(kc32 + st * 4) * 16 + wm * 4) * 64 + lane;
    const char* bb = buf + (wn * 4) * 1024;
#pragma unroll
    for (int kk = 0; kk < 4; ++kk) {
      short8 a0 = pa[(kk * 16 + 0) * 64];
      short8 a1 = pa[(kk * 16 + 1) * 64];
      short8 a2 = pa[(kk * 16 + 2) * 64];
      short8 a3 = pa[(kk * 16 + 3) * 64];
      const int ro = kk * 8192 + (rbase ^ (kk << 4));
      short8 b0 = *(const short8*)(bb + ro);
      short8 b1 = *(const short8*)(bb + ro + 1024);
      short8 b2 = *(const short8*)(bb + ro + 2048);
      short8 b3 = *(const short8*)(bb + ro + 3072);
      __builtin_amdgcn_s_setprio(1);
      acc[0][0] = MFMA16(a0, b0, acc[0][0]); acc[0][1] = MFMA16(a0, b1, acc[0][1]);
      acc[0][2] = MFMA16(a0, b2, acc[0][2]); acc[0][3] = MFMA16(a0, b3, acc[0][3]);
      acc[1][0] = MFMA16(a1, b0, acc[1][0]); acc[1][1] = MFMA16(a1, b1, acc[1][1]);
      acc[1][2] = MFMA16(a1, b2, acc[1][2]); acc[1][3] = MFMA16(a1, b3, acc[1][3]);
      acc[2][0] = MFMA16(a2, b0, acc[2][0]); acc[2][1] = MFMA16(a2, b1, acc[2][1]);
      acc[2][2] = MFMA16(a2, b2, acc[2][2]); acc[2][3] = MFMA16(a2, b3, acc[2][3]);
      acc[3][0] = MFMA16(a3, b0, acc[3][0]); acc[3][1] = MFMA16(a3, b1, acc[3][1]);
      acc[3][2] = MFMA16(a3, b2, acc[3][2]); acc[3][3] = MFMA16(a3, b3, acc[3][3]);
      __builtin_amdgcn_s_setprio(0);
    }
  }

  const size_t pb = (size_t)sk * PEL;
#pragma unroll
  for (int mi = 0; mi < 4; ++mi) {
    int mrow = wm * 64 + mi * 16 + (quad << 2);
#pragma unroll
    for (int ni = 0; ni < 4; ++ni) {
      int n = n0 + wn * 64 + ni * 16 + s_;
#pragma unroll
      for (int e = 0; e < 4; ++e)
        P2[pb + (size_t)(mrow + e) * NPD + n] = acc[mi][ni][e];
    }
  }
}

// ---------------- kernel 3: reduce partials + QRUN-d epilogue -> out fp32 ----------------
__global__ __launch_bounds__(256) void k_fin(const float* __restrict__ P2, const float* __restrict__ bd,
    const float* __restrict__ W1d, const float* __restrict__ b1d, const float* __restrict__ W2d,
    const float* __restrict__ b2d, float* __restrict__ out) {
  __shared__ float4 mc0[32];
  __shared__ float mc1[32];
  const int tid = threadIdx.x;
  if (tid < 32) {
    const float* w = W1d + tid * 6;
    mc0[tid] = make_float4(w[0] + w[2] + w[4], w[1] + w[3] + w[5], b1d[tid], W2d[tid]);
    mc1[tid] = W2d[32 + tid];
  }
  __syncthreads();
  const int idx = blockIdx.x * 256 + tid;
  const int m = idx / NPD, j = idx - m * NPD;
  float p = bd[j];
#pragma unroll
  for (int sk = 0; sk < SPLITD; ++sk) p += P2[(size_t)sk * PEL + idx];
  float s = __sinf(p), c = __cosf(p);
  float o0 = b2d[0], o1 = b2d[1];
#pragma unroll 4
  for (int mm = 0; mm < 32; ++mm) {
    float4 k = mc0[mm];
    float hh = fmaxf(fmaf(s, k.x, fmaf(c, k.y, k.z)), 0.f);
    o0 = fmaf(hh, k.w, o0);
    o1 = fmaf(hh, mc1[mm], o1);
  }
  *(float2*)&out[(size_t)m * 5120 + 2 * j] = make_float2(o0, o1);
}

extern "C" void kernel_launch(void* const* d_in, const int* in_sizes, int n_in,
                              void* d_out, int out_size, void* d_ws, size_t ws_size,
                              hipStream_t stream) {
  const float* x   = (const float*)d_in[0];
  const float* Wg  = (const float*)d_in[1];
  const float* bg  = (const float*)d_in[2];
  const float* W1g = (const float*)d_in[3];
  const float* b1g = (const float*)d_in[4];
  const float* W2g = (const float*)d_in[5];
  const float* b2g = (const float*)d_in[6];
  const float* Wu  = (const float*)d_in[7];
  const float* bu  = (const float*)d_in[8];
  const float* W1u = (const float*)d_in[9];
  const float* b1u = (const float*)d_in[10];
  const float* W2u = (const float*)d_in[11];
  const float* b2u = (const float*)d_in[12];
  const float* Wd  = (const float*)d_in[13];
  const float* bd  = (const float*)d_in[14];
  const float* W1d = (const float*)d_in[15];
  const float* b1d = (const float*)d_in[16];
  const float* W2d = (const float*)d_in[17];
  const float* b2d = (const float*)d_in[18];
  char* ws = (char*)d_ws;
  u16*  XF = (u16*)ws;                     // 2,621,440 B  (x fragments)
  u16*  HF = (u16*)(ws + 2621440);         // 14,155,776 B (h fragments; ends 16,777,216)
  float* P2 = (float*)(ws + 16777216);     // 12 x 2,621,440 = 31,457,280 B
  if (ws_size < 48234496u) return;

  k_cvt<<<dim3(160), dim3(256), 0, stream>>>(x, XF);
  k_gu<<<dim3(432), dim3(512), 0, stream>>>(XF, Wg, bg, W1g, b1g, W2g, b2g,
                                            Wu, bu, W1u, b1u, W2u, b2u, HF);
  k_down<<<dim3(240), dim3(512), 0, stream>>>(HF, Wd, P2);
  k_fin<<<dim3(2560), dim3(256), 0, stream>>>(P2, bd, W1d, b1d, W2d, b2d, (float*)d_out);
}